// Round 1
// baseline (2430.152 us; speedup 1.0000x reference)
//
#include <hip/hip_runtime.h>
#include <math.h>

// Problem constants
static constexpr int NB    = 4;      // batch
static constexpr int CDIM  = 256;    // channels
static constexpr int TOK   = 4096;   // h*w tokens
static constexpr int NHEAD = 4;
static constexpr int DHEAD = 64;

// Swizzled LDS index for 64x64 float tiles, addressed in float4 granules.
// phys = row*64 + ((col4 ^ (row & 15)) << 2)   -- keeps 16B alignment,
// spreads column-slice reads across bank quads (2-way max -> free).
__device__ __forceinline__ int swz(int row, int col4) {
    return row * 64 + (((col4) ^ (row & 15)) << 2);
}

// ---------------------------------------------------------------------------
// Kernel 1: QKV projection.  qkv[n, t, :] = x[n, :, t]^T @ W + b
// Epilogue splits into per-head q/k/v buffers laid out [n][head][t][d],
// folding mask[t] * scale into q.
// ---------------------------------------------------------------------------
__global__ __launch_bounds__(256)
void qkv_gemm(const float* __restrict__ x, const float* __restrict__ Wq,
              const float* __restrict__ bq, const float* __restrict__ mask,
              float* __restrict__ qb, float* __restrict__ kb,
              float* __restrict__ vb)
{
    const int col0 = blockIdx.x * 64;   // 0..704, spans one (part,head) d-range
    const int t0   = blockIdx.y * 64;   // token tile
    const int n    = blockIdx.z;
    const int tid  = threadIdx.x;
    const int tx   = tid & 15, ty = tid >> 4;

    __shared__ float As[32][64];   // [c_local][t_local]
    __shared__ float Bs[32][64];   // [c_local][j_local]

    float acc[4][4] = {};
    const float* xn = x + (size_t)n * CDIM * TOK;

    for (int k0 = 0; k0 < CDIM; k0 += 32) {
        __syncthreads();
        #pragma unroll
        for (int i = 0; i < 2; ++i) {
            int idx = tid + i * 256;          // 0..511 float4 slots
            int cl = idx >> 4, q4 = idx & 15;
            *(float4*)&As[cl][q4 * 4] =
                *(const float4*)(xn + (size_t)(k0 + cl) * TOK + t0 + q4 * 4);
            *(float4*)&Bs[cl][q4 * 4] =
                *(const float4*)(Wq + (size_t)(k0 + cl) * 768 + col0 + q4 * 4);
        }
        __syncthreads();
        #pragma unroll
        for (int kk = 0; kk < 32; ++kk) {
            float4 a = *(const float4*)&As[kk][ty * 4];
            float4 b = *(const float4*)&Bs[kk][tx * 4];
            float ar[4] = {a.x, a.y, a.z, a.w};
            float br[4] = {b.x, b.y, b.z, b.w};
            #pragma unroll
            for (int r = 0; r < 4; ++r)
                #pragma unroll
                for (int c = 0; c < 4; ++c)
                    acc[r][c] += ar[r] * br[c];
        }
    }

    const int part = col0 >> 8;            // 0=q 1=k 2=v (uniform per block)
    const int head = (col0 & 255) >> 6;    // uniform per block
    float* dst = (part == 0) ? qb : (part == 1) ? kb : vb;
    float4 bias = *(const float4*)(bq + col0 + tx * 4);

    #pragma unroll
    for (int r = 0; r < 4; ++r) {
        int t = t0 + ty * 4 + r;
        float4 v;
        v.x = acc[r][0] + bias.x;
        v.y = acc[r][1] + bias.y;
        v.z = acc[r][2] + bias.z;
        v.w = acc[r][3] + bias.w;
        if (part == 0) {
            float mv = mask[(size_t)n * TOK + t] * 0.0625f;  // fold mask*scale
            v.x *= mv; v.y *= mv; v.z *= mv; v.w *= mv;
        }
        *(float4*)(dst + (((size_t)(n * NHEAD + head) * TOK + t) * DHEAD + tx * 4)) = v;
    }
}

// ---------------------------------------------------------------------------
// Kernel 2: flash attention, fp32.  One block = 64 query rows of one (n,head).
// ---------------------------------------------------------------------------
__global__ __launch_bounds__(256)
void attn(const float* __restrict__ qb, const float* __restrict__ kb,
          const float* __restrict__ vb, float* __restrict__ out)
{
    const int t0 = blockIdx.x * 64;   // query tile
    const int h  = blockIdx.y;
    const int n  = blockIdx.z;
    const int tid = threadIdx.x;
    const int tx = tid & 15, ty = tid >> 4;

    __shared__ float Qs[64 * 64];
    __shared__ float Ks[64 * 64];
    __shared__ float Vs[64 * 64];
    __shared__ float Ps[64 * 64];   // P tile; reused as output-transpose buffer

    const size_t base = (size_t)(n * NHEAD + h) * TOK * DHEAD;
    const float* Qg = qb + base + (size_t)t0 * DHEAD;

    #pragma unroll
    for (int i = 0; i < 4; ++i) {           // load Q tile (swizzled)
        int idx = tid + i * 256;
        int row = idx >> 4, c4 = idx & 15;
        *(float4*)&Qs[swz(row, c4)] = *(const float4*)(Qg + row * 64 + c4 * 4);
    }

    float m[4], l[4], o[4][4];
    #pragma unroll
    for (int r = 0; r < 4; ++r) {
        m[r] = -1e30f; l[r] = 0.f;
        #pragma unroll
        for (int c = 0; c < 4; ++c) o[r][c] = 0.f;
    }

    for (int kt = 0; kt < TOK / 64; ++kt) {
        __syncthreads();
        const float* Kg = kb + base + (size_t)kt * 64 * DHEAD;
        const float* Vg = vb + base + (size_t)kt * 64 * DHEAD;
        #pragma unroll
        for (int i = 0; i < 4; ++i) {
            int idx = tid + i * 256;
            int row = idx >> 4, c4 = idx & 15;
            *(float4*)&Ks[swz(row, c4)] = *(const float4*)(Kg + row * 64 + c4 * 4);
            *(float4*)&Vs[swz(row, c4)] = *(const float4*)(Vg + row * 64 + c4 * 4);
        }
        __syncthreads();

        // S = Q K^T  (scale & mask already folded into Q)
        float s[4][4] = {};
        #pragma unroll
        for (int d4 = 0; d4 < 16; ++d4) {
            float4 qv[4], kv[4];
            #pragma unroll
            for (int r = 0; r < 4; ++r) qv[r] = *(const float4*)&Qs[swz(ty * 4 + r, d4)];
            #pragma unroll
            for (int c = 0; c < 4; ++c) kv[c] = *(const float4*)&Ks[swz(tx * 4 + c, d4)];
            #pragma unroll
            for (int r = 0; r < 4; ++r)
                #pragma unroll
                for (int c = 0; c < 4; ++c)
                    s[r][c] += qv[r].x * kv[c].x + qv[r].y * kv[c].y
                             + qv[r].z * kv[c].z + qv[r].w * kv[c].w;
        }

        // online softmax (rows ty*4+r; reduce across 16 tx lanes)
        #pragma unroll
        for (int r = 0; r < 4; ++r) {
            float rm = fmaxf(fmaxf(s[r][0], s[r][1]), fmaxf(s[r][2], s[r][3]));
            #pragma unroll
            for (int off = 1; off < 16; off <<= 1) rm = fmaxf(rm, __shfl_xor(rm, off));
            float mn = fmaxf(m[r], rm);
            float alpha = __expf(m[r] - mn);
            float p[4], rs = 0.f;
            #pragma unroll
            for (int c = 0; c < 4; ++c) { p[c] = __expf(s[r][c] - mn); rs += p[c]; }
            #pragma unroll
            for (int off = 1; off < 16; off <<= 1) rs += __shfl_xor(rs, off);
            m[r] = mn;
            l[r] = l[r] * alpha + rs;
            #pragma unroll
            for (int c = 0; c < 4; ++c) o[r][c] *= alpha;
            float4 pv = {p[0], p[1], p[2], p[3]};
            *(float4*)&Ps[swz(ty * 4 + r, tx)] = pv;
        }
        __syncthreads();

        // O += P V
        #pragma unroll
        for (int j4 = 0; j4 < 16; ++j4) {
            float4 pr[4];
            #pragma unroll
            for (int r = 0; r < 4; ++r) pr[r] = *(const float4*)&Ps[swz(ty * 4 + r, j4)];
            #pragma unroll
            for (int jj = 0; jj < 4; ++jj) {
                float4 vv = *(const float4*)&Vs[swz(j4 * 4 + jj, tx)];
                #pragma unroll
                for (int r = 0; r < 4; ++r) {
                    float pw = ((const float*)&pr[r])[jj];
                    o[r][0] += pw * vv.x;
                    o[r][1] += pw * vv.y;
                    o[r][2] += pw * vv.z;
                    o[r][3] += pw * vv.w;
                }
            }
        }
    }

    // epilogue: normalize, transpose via LDS (reuse Ps) to channel-major
    __syncthreads();
    #pragma unroll
    for (int c = 0; c < 4; ++c) {
        float4 ov;
        ov.x = o[0][c] / l[0];
        ov.y = o[1][c] / l[1];
        ov.z = o[2][c] / l[2];
        ov.w = o[3][c] / l[3];
        *(float4*)&Ps[swz(tx * 4 + c, ty)] = ov;   // Os[ch_local][tok4]
    }
    __syncthreads();
    float* og = out + ((size_t)n * CDIM + h * DHEAD) * TOK + t0;
    #pragma unroll
    for (int i = 0; i < 4; ++i) {
        int idx = tid + i * 256;
        int ch = idx >> 4, t4 = idx & 15;
        *(float4*)(og + (size_t)ch * TOK + t4 * 4) = *(const float4*)&Ps[swz(ch, t4)];
    }
}

// ---------------------------------------------------------------------------
extern "C" void kernel_launch(void* const* d_in, const int* in_sizes, int n_in,
                              void* d_out, int out_size, void* d_ws, size_t ws_size,
                              hipStream_t stream)
{
    const float* x    = (const float*)d_in[0];   // (4,256,64,64)
    const float* mask = (const float*)d_in[1];   // (4,1,64,64)
    const float* Wq   = (const float*)d_in[2];   // (256,768)
    const float* bq   = (const float*)d_in[3];   // (768,)
    float* out = (float*)d_out;                  // (4,256,64,64)

    float* qb = (float*)d_ws;                    // [n][head][t][d] 16 MB each
    float* kb = qb + (size_t)NB * NHEAD * TOK * DHEAD;
    float* vb = kb + (size_t)NB * NHEAD * TOK * DHEAD;

    qkv_gemm<<<dim3(12, 64, 4), 256, 0, stream>>>(x, Wq, bq, mask, qb, kb, vb);
    attn<<<dim3(64, 4, 4), 256, 0, stream>>>(qb, kb, vb, out);
}

// Round 2
// 481.703 us; speedup vs baseline: 5.0449x; 5.0449x over previous
//
#include <hip/hip_runtime.h>
#include <math.h>

static constexpr int NB    = 4;
static constexpr int CDIM  = 256;
static constexpr int TOK   = 4096;
static constexpr int NHEAD = 4;
static constexpr int DHEAD = 64;

typedef short           bf16x8_t  __attribute__((ext_vector_type(8)));
typedef float           f32x4_t   __attribute__((ext_vector_type(4)));
typedef unsigned short  ushort8_t __attribute__((ext_vector_type(8)));

__device__ __forceinline__ unsigned short f2bf_rne(float f) {
    unsigned x = __builtin_bit_cast(unsigned, f);
    x += 0x7fffu + ((x >> 16) & 1u);
    return (unsigned short)(x >> 16);
}
__device__ __forceinline__ float bf2f(unsigned short u) {
    return __builtin_bit_cast(float, (unsigned)u << 16);
}

// ---------------------------------------------------------------------------
// Kernel 1: QKV projection (fp32 VALU GEMM, 6.4 GFLOP).
// Epilogue emits bf16 hi/lo planes:
//   qhi/qlo, khi/klo : [n][head][t][d]   (mask*scale folded into q)
//   vthi/vtlo        : [n][head][d][t]   (transposed for MFMA B-frags)
// ---------------------------------------------------------------------------
__global__ __launch_bounds__(256)
void qkv_gemm(const float* __restrict__ x, const float* __restrict__ Wq,
              const float* __restrict__ bq, const float* __restrict__ mask,
              unsigned short* __restrict__ qhi, unsigned short* __restrict__ qlo,
              unsigned short* __restrict__ khi, unsigned short* __restrict__ klo,
              unsigned short* __restrict__ vthi, unsigned short* __restrict__ vtlo)
{
    const int col0 = blockIdx.x * 64;
    const int t0   = blockIdx.y * 64;
    const int n    = blockIdx.z;
    const int tid  = threadIdx.x;
    const int tx   = tid & 15, ty = tid >> 4;

    __shared__ float As[32][64];
    __shared__ float Bs[32][64];

    float acc[4][4] = {};
    const float* xn = x + (size_t)n * CDIM * TOK;

    for (int k0 = 0; k0 < CDIM; k0 += 32) {
        __syncthreads();
        #pragma unroll
        for (int i = 0; i < 2; ++i) {
            int idx = tid + i * 256;
            int cl = idx >> 4, q4 = idx & 15;
            *(float4*)&As[cl][q4 * 4] =
                *(const float4*)(xn + (size_t)(k0 + cl) * TOK + t0 + q4 * 4);
            *(float4*)&Bs[cl][q4 * 4] =
                *(const float4*)(Wq + (size_t)(k0 + cl) * 768 + col0 + q4 * 4);
        }
        __syncthreads();
        #pragma unroll
        for (int kk = 0; kk < 32; ++kk) {
            float4 a = *(const float4*)&As[kk][ty * 4];
            float4 b = *(const float4*)&Bs[kk][tx * 4];
            float ar[4] = {a.x, a.y, a.z, a.w};
            float br[4] = {b.x, b.y, b.z, b.w};
            #pragma unroll
            for (int r = 0; r < 4; ++r)
                #pragma unroll
                for (int c = 0; c < 4; ++c)
                    acc[r][c] += ar[r] * br[c];
        }
    }

    const int part = col0 >> 8;            // 0=q 1=k 2=v
    const int head = (col0 & 255) >> 6;
    const size_t hb = (size_t)(n * NHEAD + head) * TOK * DHEAD;
    float4 bias = *(const float4*)(bq + col0 + tx * 4);
    float bb[4] = {bias.x, bias.y, bias.z, bias.w};

    float vals[4][4];
    #pragma unroll
    for (int r = 0; r < 4; ++r)
        #pragma unroll
        for (int c = 0; c < 4; ++c)
            vals[r][c] = acc[r][c] + bb[c];

    if (part == 0) {
        #pragma unroll
        for (int r = 0; r < 4; ++r) {
            int t = t0 + ty * 4 + r;
            float mv = mask[(size_t)n * TOK + t] * 0.0625f;
            #pragma unroll
            for (int c = 0; c < 4; ++c) vals[r][c] *= mv;
        }
    }

    if (part <= 1) {
        unsigned short* hp = (part == 0) ? qhi : khi;
        unsigned short* lp = (part == 0) ? qlo : klo;
        #pragma unroll
        for (int r = 0; r < 4; ++r) {
            int t = t0 + ty * 4 + r;
            ushort4 h, l;
            unsigned short* hc = (unsigned short*)&h;
            unsigned short* lc = (unsigned short*)&l;
            #pragma unroll
            for (int c = 0; c < 4; ++c) {
                hc[c] = f2bf_rne(vals[r][c]);
                lc[c] = f2bf_rne(vals[r][c] - bf2f(hc[c]));
            }
            *(ushort4*)&hp[hb + (size_t)t * DHEAD + tx * 4] = h;
            *(ushort4*)&lp[hb + (size_t)t * DHEAD + tx * 4] = l;
        }
    } else {
        #pragma unroll
        for (int c = 0; c < 4; ++c) {
            int d = tx * 4 + c;
            ushort4 h, l;
            unsigned short* hc = (unsigned short*)&h;
            unsigned short* lc = (unsigned short*)&l;
            #pragma unroll
            for (int r = 0; r < 4; ++r) {
                hc[r] = f2bf_rne(vals[r][c]);
                lc[r] = f2bf_rne(vals[r][c] - bf2f(hc[r]));
            }
            *(ushort4*)&vthi[hb + (size_t)d * TOK + t0 + ty * 4] = h;
            *(ushort4*)&vtlo[hb + (size_t)d * TOK + t0 + ty * 4] = l;
        }
    }
}

// ---------------------------------------------------------------------------
// Kernel 2: flash attention on MFMA (bf16 hi/lo split, 3-product emulation).
// 4 waves/block, 64 q-rows per block, 64-key tiles, XOR-swizzled LDS.
// ---------------------------------------------------------------------------
#define MFMA(a, b, c) __builtin_amdgcn_mfma_f32_16x16x32_bf16((a), (b), (c), 0, 0, 0)

__global__ __launch_bounds__(256)
void attn_mfma(const unsigned short* __restrict__ qhi, const unsigned short* __restrict__ qlo,
               const unsigned short* __restrict__ khi, const unsigned short* __restrict__ klo,
               const unsigned short* __restrict__ vthi, const unsigned short* __restrict__ vtlo,
               float* __restrict__ out)
{
    __shared__ __align__(16) unsigned short smem[32768];   // 64 KiB
    constexpr int QHI = 0,     QLO = 4096,  KHI = 8192,  KLO = 12288;
    constexpr int VHI = 16384, VLO = 20480, PHI = 24576, PLO = 28672;

    // XCD-aware decode: blocks sharing (n,head) land on the same XCD.
    const int bid  = blockIdx.x;
    const int p    = (bid & 7) | (((bid >> 3) & 1) << 3);   // (n,head) pair 0..15
    const int tile = bid >> 4;                              // 0..63
    const int n = p >> 2, h = p & 3;
    const int t0 = tile * 64;

    const int tid  = threadIdx.x;
    const int lane = tid & 63, w = tid >> 6;
    const int l15  = lane & 15, g = lane >> 4;

    const size_t base = (size_t)(n * NHEAD + h) * TOK * DHEAD;

    // ---- stage Q (both planes, swizzled) ----
    {
        int gr = tid & 7;
        #pragma unroll
        for (int ph = 0; ph < 2; ++ph) {
            int r2 = ((tid >> 3) & 31) + ph * 32;
            size_t src = base + (size_t)(t0 + r2) * DHEAD + gr * 8;
            int dst = r2 * 64 + ((gr ^ (r2 & 7)) << 3);
            *(ushort8_t*)&smem[QHI + dst] = *(const ushort8_t*)&qhi[src];
            *(ushort8_t*)&smem[QLO + dst] = *(const ushort8_t*)&qlo[src];
        }
    }
    __syncthreads();

    // ---- hoist Q fragments (A-operand: row = l15, k-octet = ks*4+g) ----
    bf16x8_t qh[2], ql[2];
    #pragma unroll
    for (int ks = 0; ks < 2; ++ks) {
        int row = w * 16 + l15, gr = ks * 4 + g;
        int idx = row * 64 + ((gr ^ (row & 7)) << 3);
        qh[ks] = __builtin_bit_cast(bf16x8_t, *(const ushort8_t*)&smem[QHI + idx]);
        ql[ks] = __builtin_bit_cast(bf16x8_t, *(const ushort8_t*)&smem[QLO + idx]);
    }

    float mreg[4], lsum[4];
    f32x4_t oa[4];
    #pragma unroll
    for (int r = 0; r < 4; ++r) { mreg[r] = -1e30f; lsum[r] = 0.f; }
    #pragma unroll
    for (int db = 0; db < 4; ++db) oa[db] = (f32x4_t){0.f, 0.f, 0.f, 0.f};

    for (int kt = 0; kt < TOK / 64; ++kt) {
        __syncthreads();
        // ---- stage K (row-major) and V^T (row=d) tiles, swizzled ----
        {
            int gr = tid & 7;
            #pragma unroll
            for (int ph = 0; ph < 2; ++ph) {
                int r2 = ((tid >> 3) & 31) + ph * 32;
                int dst = r2 * 64 + ((gr ^ (r2 & 7)) << 3);
                size_t ksrc = base + (size_t)(kt * 64 + r2) * DHEAD + gr * 8;
                size_t vsrc = base + (size_t)r2 * TOK + kt * 64 + gr * 8;
                *(ushort8_t*)&smem[KHI + dst] = *(const ushort8_t*)&khi[ksrc];
                *(ushort8_t*)&smem[KLO + dst] = *(const ushort8_t*)&klo[ksrc];
                *(ushort8_t*)&smem[VHI + dst] = *(const ushort8_t*)&vthi[vsrc];
                *(ushort8_t*)&smem[VLO + dst] = *(const ushort8_t*)&vtlo[vsrc];
            }
        }
        __syncthreads();

        // ---- S = Q K^T (3-product hi/lo emulation) ----
        f32x4_t sa[4];
        #pragma unroll
        for (int kb = 0; kb < 4; ++kb) sa[kb] = (f32x4_t){0.f, 0.f, 0.f, 0.f};
        #pragma unroll
        for (int ks = 0; ks < 2; ++ks) {
            #pragma unroll
            for (int kb = 0; kb < 4; ++kb) {
                int row = kb * 16 + l15, gr = ks * 4 + g;
                int idx = row * 64 + ((gr ^ (row & 7)) << 3);
                bf16x8_t kh = __builtin_bit_cast(bf16x8_t, *(const ushort8_t*)&smem[KHI + idx]);
                bf16x8_t kl = __builtin_bit_cast(bf16x8_t, *(const ushort8_t*)&smem[KLO + idx]);
                sa[kb] = MFMA(qh[ks], kh, sa[kb]);
                sa[kb] = MFMA(qh[ks], kl, sa[kb]);
                sa[kb] = MFMA(ql[ks], kh, sa[kb]);
            }
        }

        // ---- online softmax; P -> bf16 hi/lo in LDS ----
        #pragma unroll
        for (int r = 0; r < 4; ++r) {
            float mx = fmaxf(fmaxf(sa[0][r], sa[1][r]), fmaxf(sa[2][r], sa[3][r]));
            #pragma unroll
            for (int off = 1; off < 16; off <<= 1) mx = fmaxf(mx, __shfl_xor(mx, off));
            float mn = fmaxf(mreg[r], mx);
            float al = __expf(mreg[r] - mn);
            mreg[r] = mn;

            int qrow = w * 16 + 4 * g + r;
            float rs = 0.f;
            #pragma unroll
            for (int kb = 0; kb < 4; ++kb) {
                float pv = __expf(sa[kb][r] - mn);
                rs += pv;
                unsigned pb = __builtin_bit_cast(unsigned, pv);
                unsigned short ph16 = (unsigned short)(pb >> 16);
                float rem = pv - bf2f(ph16);
                unsigned short pl16 = (unsigned short)(__builtin_bit_cast(unsigned, rem) >> 16);
                int col = kb * 16 + l15;
                int pidx = qrow * 64 + ((((col >> 3)) ^ (qrow & 7)) << 3) + (col & 7);
                smem[PHI + pidx] = ph16;
                smem[PLO + pidx] = pl16;
            }
            #pragma unroll
            for (int off = 1; off < 16; off <<= 1) rs += __shfl_xor(rs, off);
            lsum[r] = lsum[r] * al + rs;
            #pragma unroll
            for (int db = 0; db < 4; ++db) oa[db][r] *= al;
        }
        __syncthreads();

        // ---- O += P V (A = P rows q, B = V^T rows d) ----
        #pragma unroll
        for (int ks = 0; ks < 2; ++ks) {
            int prow = w * 16 + l15, gr = ks * 4 + g;
            int pidx = prow * 64 + ((gr ^ (prow & 7)) << 3);
            bf16x8_t pah = __builtin_bit_cast(bf16x8_t, *(const ushort8_t*)&smem[PHI + pidx]);
            bf16x8_t pal = __builtin_bit_cast(bf16x8_t, *(const ushort8_t*)&smem[PLO + pidx]);
            #pragma unroll
            for (int db = 0; db < 4; ++db) {
                int vrow = db * 16 + l15;
                int vidx = vrow * 64 + ((gr ^ (vrow & 7)) << 3);
                bf16x8_t vh = __builtin_bit_cast(bf16x8_t, *(const ushort8_t*)&smem[VHI + vidx]);
                bf16x8_t vl = __builtin_bit_cast(bf16x8_t, *(const ushort8_t*)&smem[VLO + vidx]);
                oa[db] = MFMA(pah, vh, oa[db]);
                oa[db] = MFMA(pah, vl, oa[db]);
                oa[db] = MFMA(pal, vh, oa[db]);
            }
        }
    }

    // ---- epilogue: normalize, transpose to channel-major via LDS ----
    __syncthreads();
    float* Os = (float*)&smem[KHI];   // 16 KiB scratch over K planes
    #pragma unroll
    for (int db = 0; db < 4; ++db) {
        int d = db * 16 + l15;
        #pragma unroll
        for (int r = 0; r < 4; ++r) {
            int q = w * 16 + 4 * g + r;
            int oidx = d * 64 + (((q >> 2) ^ (d & 15)) << 2) + (q & 3);
            Os[oidx] = oa[db][r] / lsum[r];
        }
    }
    __syncthreads();
    {
        int d = tid >> 2, tg = tid & 3;
        float* og = out + ((size_t)n * CDIM + h * DHEAD + d) * TOK + t0;
        #pragma unroll
        for (int j = 0; j < 4; ++j) {
            int q4 = j * 4 + tg;
            float4 v = *(const float4*)&Os[d * 64 + ((q4 ^ (d & 15)) << 2)];
            *(float4*)&og[q4 * 4] = v;
        }
    }
}

// ---------------------------------------------------------------------------
extern "C" void kernel_launch(void* const* d_in, const int* in_sizes, int n_in,
                              void* d_out, int out_size, void* d_ws, size_t ws_size,
                              hipStream_t stream)
{
    const float* x    = (const float*)d_in[0];
    const float* mask = (const float*)d_in[1];
    const float* Wq   = (const float*)d_in[2];
    const float* bq   = (const float*)d_in[3];
    float* out = (float*)d_out;

    const size_t PL = (size_t)NB * NHEAD * TOK * DHEAD;   // 4,194,304 elems
    unsigned short* qhi  = (unsigned short*)d_ws;
    unsigned short* qlo  = qhi  + PL;
    unsigned short* khi  = qlo  + PL;
    unsigned short* klo  = khi  + PL;
    unsigned short* vthi = klo  + PL;
    unsigned short* vtlo = vthi + PL;

    qkv_gemm<<<dim3(12, 64, 4), 256, 0, stream>>>(x, Wq, bq, mask,
                                                  qhi, qlo, khi, klo, vthi, vtlo);
    attn_mfma<<<dim3(1024), 256, 0, stream>>>(qhi, qlo, khi, klo, vthi, vtlo, out);
}

// Round 3
// 457.730 us; speedup vs baseline: 5.3091x; 1.0524x over previous
//
#include <hip/hip_runtime.h>
#include <math.h>

static constexpr int NB    = 4;
static constexpr int CDIM  = 256;
static constexpr int TOK   = 4096;
static constexpr int NHEAD = 4;
static constexpr int DHEAD = 64;
static constexpr int NT    = TOK / 64;

typedef short           bf16x8_t  __attribute__((ext_vector_type(8)));
typedef float           f32x4_t   __attribute__((ext_vector_type(4)));
typedef unsigned short  ushort8_t __attribute__((ext_vector_type(8)));

__device__ __forceinline__ unsigned short f2bf_rne(float f) {
    unsigned x = __builtin_bit_cast(unsigned, f);
    x += 0x7fffu + ((x >> 16) & 1u);
    return (unsigned short)(x >> 16);
}
__device__ __forceinline__ float bf2f(unsigned short u) {
    return __builtin_bit_cast(float, (unsigned)u << 16);
}

// ---------------------------------------------------------------------------
// Kernel 1: QKV projection (fp32 VALU GEMM). Epilogue emits bf16 hi/lo planes.
// mask * scale * log2(e) folded into q so attention softmax can use exp2.
// ---------------------------------------------------------------------------
__global__ __launch_bounds__(256)
void qkv_gemm(const float* __restrict__ x, const float* __restrict__ Wq,
              const float* __restrict__ bq, const float* __restrict__ mask,
              unsigned short* __restrict__ qhi, unsigned short* __restrict__ qlo,
              unsigned short* __restrict__ khi, unsigned short* __restrict__ klo,
              unsigned short* __restrict__ vthi, unsigned short* __restrict__ vtlo)
{
    const int col0 = blockIdx.x * 64;
    const int t0   = blockIdx.y * 64;
    const int n    = blockIdx.z;
    const int tid  = threadIdx.x;
    const int tx   = tid & 15, ty = tid >> 4;

    __shared__ float As[32][64];
    __shared__ float Bs[32][64];

    float acc[4][4] = {};
    const float* xn = x + (size_t)n * CDIM * TOK;

    for (int k0 = 0; k0 < CDIM; k0 += 32) {
        __syncthreads();
        #pragma unroll
        for (int i = 0; i < 2; ++i) {
            int idx = tid + i * 256;
            int cl = idx >> 4, q4 = idx & 15;
            *(float4*)&As[cl][q4 * 4] =
                *(const float4*)(xn + (size_t)(k0 + cl) * TOK + t0 + q4 * 4);
            *(float4*)&Bs[cl][q4 * 4] =
                *(const float4*)(Wq + (size_t)(k0 + cl) * 768 + col0 + q4 * 4);
        }
        __syncthreads();
        #pragma unroll
        for (int kk = 0; kk < 32; ++kk) {
            float4 a = *(const float4*)&As[kk][ty * 4];
            float4 b = *(const float4*)&Bs[kk][tx * 4];
            float ar[4] = {a.x, a.y, a.z, a.w};
            float br[4] = {b.x, b.y, b.z, b.w};
            #pragma unroll
            for (int r = 0; r < 4; ++r)
                #pragma unroll
                for (int c = 0; c < 4; ++c)
                    acc[r][c] += ar[r] * br[c];
        }
    }

    const int part = col0 >> 8;            // 0=q 1=k 2=v
    const int head = (col0 & 255) >> 6;
    const size_t hb = (size_t)(n * NHEAD + head) * TOK * DHEAD;
    float4 bias = *(const float4*)(bq + col0 + tx * 4);
    float bb[4] = {bias.x, bias.y, bias.z, bias.w};

    float vals[4][4];
    #pragma unroll
    for (int r = 0; r < 4; ++r)
        #pragma unroll
        for (int c = 0; c < 4; ++c)
            vals[r][c] = acc[r][c] + bb[c];

    if (part == 0) {
        #pragma unroll
        for (int r = 0; r < 4; ++r) {
            int t = t0 + ty * 4 + r;
            // fold mask * (1/16) * log2(e): softmax then uses exp2 directly
            float mv = mask[(size_t)n * TOK + t] * 0.0625f * 1.4426950408889634f;
            #pragma unroll
            for (int c = 0; c < 4; ++c) vals[r][c] *= mv;
        }
    }

    if (part <= 1) {
        unsigned short* hp = (part == 0) ? qhi : khi;
        unsigned short* lp = (part == 0) ? qlo : klo;
        #pragma unroll
        for (int r = 0; r < 4; ++r) {
            int t = t0 + ty * 4 + r;
            ushort4 hh, ll;
            unsigned short* hc = (unsigned short*)&hh;
            unsigned short* lc = (unsigned short*)&ll;
            #pragma unroll
            for (int c = 0; c < 4; ++c) {
                hc[c] = f2bf_rne(vals[r][c]);
                lc[c] = f2bf_rne(vals[r][c] - bf2f(hc[c]));
            }
            *(ushort4*)&hp[hb + (size_t)t * DHEAD + tx * 4] = hh;
            *(ushort4*)&lp[hb + (size_t)t * DHEAD + tx * 4] = ll;
        }
    } else {
        #pragma unroll
        for (int c = 0; c < 4; ++c) {
            int d = tx * 4 + c;
            ushort4 hh, ll;
            unsigned short* hc = (unsigned short*)&hh;
            unsigned short* lc = (unsigned short*)&ll;
            #pragma unroll
            for (int r = 0; r < 4; ++r) {
                hc[r] = f2bf_rne(vals[r][c]);
                lc[r] = f2bf_rne(vals[r][c] - bf2f(hc[r]));
            }
            *(ushort4*)&vthi[hb + (size_t)d * TOK + t0 + ty * 4] = hh;
            *(ushort4*)&vtlo[hb + (size_t)d * TOK + t0 + ty * 4] = ll;
        }
    }
}

// ---------------------------------------------------------------------------
// Kernel 2: flash attention on MFMA, latency-hiding restructure.
//  - 32 KiB LDS: K region (P and prologue-Q alias it) + V region.
//  - register-staged prefetch of K/V(kt+1): loads at top, ds_write at tail.
//  - lgkm-only barriers (never drain vmcnt -> prefetch stays in flight).
//  - P is wave-private (write->read needs only wave-local lgkmcnt(0)).
// ---------------------------------------------------------------------------
#define MFMA(a, b, c) __builtin_amdgcn_mfma_f32_16x16x32_bf16((a), (b), (c), 0, 0, 0)
#define LGKM_BAR() asm volatile("s_waitcnt lgkmcnt(0)\n\ts_barrier" ::: "memory")
#define LGKM0()    asm volatile("s_waitcnt lgkmcnt(0)" ::: "memory")

__global__ __launch_bounds__(256, 4)
void attn_mfma(const unsigned short* __restrict__ qhi, const unsigned short* __restrict__ qlo,
               const unsigned short* __restrict__ khi, const unsigned short* __restrict__ klo,
               const unsigned short* __restrict__ vthi, const unsigned short* __restrict__ vtlo,
               float* __restrict__ out)
{
    __shared__ __align__(16) unsigned short smem[16384];   // 32 KiB
    constexpr int KP_HI = 0, KP_LO = 4096, V_HI = 8192, V_LO = 12288;

    const int bid  = blockIdx.x;
    const int p    = (bid & 7) | (((bid >> 3) & 1) << 3);
    const int tile = bid >> 4;
    const int n = p >> 2, h = p & 3;
    const int t0 = tile * 64;

    const int tid  = threadIdx.x;
    const int lane = tid & 63, w = tid >> 6;
    const int l15  = lane & 15, g = lane >> 4;
    const int gr   = tid & 7, r2 = (tid >> 3) & 31;
    const int dst0 = r2 * 64 + ((gr ^ (r2 & 7)) << 3);   // swizzled LDS slot

    const size_t base = (size_t)(n * NHEAD + h) * TOK * DHEAD;

    // ---- prologue: issue Q loads, then K/V(0) loads (Q waited first) ----
    const size_t qsrc = base + (size_t)(t0 + r2) * DHEAD + gr * 8;
    ushort8_t tqh0 = *(const ushort8_t*)&qhi[qsrc];
    ushort8_t tqh1 = *(const ushort8_t*)&qhi[qsrc + 32 * DHEAD];
    ushort8_t tql0 = *(const ushort8_t*)&qlo[qsrc];
    ushort8_t tql1 = *(const ushort8_t*)&qlo[qsrc + 32 * DHEAD];

    ushort8_t skh0, skh1, skl0, skl1, svh0, svh1, svl0, svl1;
    {
        size_t ks = base + (size_t)r2 * DHEAD + gr * 8;
        size_t vs = base + (size_t)r2 * TOK + gr * 8;
        skh0 = *(const ushort8_t*)&khi[ks];
        skh1 = *(const ushort8_t*)&khi[ks + 32 * DHEAD];
        skl0 = *(const ushort8_t*)&klo[ks];
        skl1 = *(const ushort8_t*)&klo[ks + 32 * DHEAD];
        svh0 = *(const ushort8_t*)&vthi[vs];
        svh1 = *(const ushort8_t*)&vthi[vs + 32 * TOK];
        svl0 = *(const ushort8_t*)&vtlo[vs];
        svl1 = *(const ushort8_t*)&vtlo[vs + 32 * TOK];
    }

    // stage Q into the K region (alias; consumed before K(0) is written)
    *(ushort8_t*)&smem[KP_HI + dst0]        = tqh0;
    *(ushort8_t*)&smem[KP_HI + dst0 + 2048] = tqh1;
    *(ushort8_t*)&smem[KP_LO + dst0]        = tql0;
    *(ushort8_t*)&smem[KP_LO + dst0 + 2048] = tql1;
    __syncthreads();

    bf16x8_t qh[2], ql[2];
    #pragma unroll
    for (int ks = 0; ks < 2; ++ks) {
        int row = w * 16 + l15, g2 = ks * 4 + g;
        int idx = row * 64 + ((g2 ^ (row & 7)) << 3);
        qh[ks] = __builtin_bit_cast(bf16x8_t, *(const ushort8_t*)&smem[KP_HI + idx]);
        ql[ks] = __builtin_bit_cast(bf16x8_t, *(const ushort8_t*)&smem[KP_LO + idx]);
    }
    LGKM_BAR();   // all waves finished reading Q before K(0) overwrites it

    // write K/V(0)
    *(ushort8_t*)&smem[KP_HI + dst0]        = skh0;
    *(ushort8_t*)&smem[KP_HI + dst0 + 2048] = skh1;
    *(ushort8_t*)&smem[KP_LO + dst0]        = skl0;
    *(ushort8_t*)&smem[KP_LO + dst0 + 2048] = skl1;
    *(ushort8_t*)&smem[V_HI + dst0]         = svh0;
    *(ushort8_t*)&smem[V_HI + dst0 + 2048]  = svh1;
    *(ushort8_t*)&smem[V_LO + dst0]         = svl0;
    *(ushort8_t*)&smem[V_LO + dst0 + 2048]  = svl1;

    float mreg[4], lsum[4];
    f32x4_t oa[4];
    #pragma unroll
    for (int r = 0; r < 4; ++r) { mreg[r] = -1e30f; lsum[r] = 0.f; }
    #pragma unroll
    for (int db = 0; db < 4; ++db) oa[db] = (f32x4_t){0.f, 0.f, 0.f, 0.f};

    for (int kt = 0; kt < NT; ++kt) {
        LGKM_BAR();   // staged K/V(kt) visible (lgkm-only: prefetch stays in flight)

        // ---- issue prefetch loads for kt+1 (consumed at tail ds_write) ----
        if (kt + 1 < NT) {
            size_t ks = base + (size_t)((kt + 1) * 64 + r2) * DHEAD + gr * 8;
            size_t vs = base + (size_t)r2 * TOK + (kt + 1) * 64 + gr * 8;
            skh0 = *(const ushort8_t*)&khi[ks];
            skh1 = *(const ushort8_t*)&khi[ks + 32 * DHEAD];
            skl0 = *(const ushort8_t*)&klo[ks];
            skl1 = *(const ushort8_t*)&klo[ks + 32 * DHEAD];
            svh0 = *(const ushort8_t*)&vthi[vs];
            svh1 = *(const ushort8_t*)&vthi[vs + 32 * TOK];
            svl0 = *(const ushort8_t*)&vtlo[vs];
            svl1 = *(const ushort8_t*)&vtlo[vs + 32 * TOK];
        }

        // ---- S = Q K^T (3-product hi/lo emulation) ----
        f32x4_t sa[4];
        #pragma unroll
        for (int kb = 0; kb < 4; ++kb) sa[kb] = (f32x4_t){0.f, 0.f, 0.f, 0.f};
        __builtin_amdgcn_s_setprio(1);
        #pragma unroll
        for (int ks = 0; ks < 2; ++ks) {
            #pragma unroll
            for (int kb = 0; kb < 4; ++kb) {
                int row = kb * 16 + l15, g2 = ks * 4 + g;
                int idx = row * 64 + ((g2 ^ (row & 7)) << 3);
                bf16x8_t kh = __builtin_bit_cast(bf16x8_t, *(const ushort8_t*)&smem[KP_HI + idx]);
                bf16x8_t kl = __builtin_bit_cast(bf16x8_t, *(const ushort8_t*)&smem[KP_LO + idx]);
                sa[kb] = MFMA(qh[ks], kh, sa[kb]);
                sa[kb] = MFMA(qh[ks], kl, sa[kb]);
                sa[kb] = MFMA(ql[ks], kh, sa[kb]);
            }
        }
        __builtin_amdgcn_s_setprio(0);

        LGKM_BAR();   // all waves done reading K(kt) -> P may overwrite region

        // ---- online softmax (exp2 path); P hi/lo -> K region (wave-private rows) ----
        #pragma unroll
        for (int r = 0; r < 4; ++r) {
            float mx = fmaxf(fmaxf(sa[0][r], sa[1][r]), fmaxf(sa[2][r], sa[3][r]));
            #pragma unroll
            for (int off = 1; off < 16; off <<= 1) mx = fmaxf(mx, __shfl_xor(mx, off));
            float mn = fmaxf(mreg[r], mx);
            float al = __builtin_amdgcn_exp2f(mreg[r] - mn);
            mreg[r] = mn;

            int qrow = w * 16 + 4 * g + r;
            float rs = 0.f;
            #pragma unroll
            for (int kb = 0; kb < 4; ++kb) {
                float pv = __builtin_amdgcn_exp2f(sa[kb][r] - mn);
                rs += pv;
                unsigned pb = __builtin_bit_cast(unsigned, pv);
                unsigned short ph16 = (unsigned short)(pb >> 16);
                float rem = pv - bf2f(ph16);
                unsigned short pl16 = (unsigned short)(__builtin_bit_cast(unsigned, rem) >> 16);
                int col = kb * 16 + l15;
                int pidx = qrow * 64 + ((((col >> 3)) ^ (qrow & 7)) << 3) + (col & 7);
                smem[KP_HI + pidx] = ph16;
                smem[KP_LO + pidx] = pl16;
            }
            #pragma unroll
            for (int off = 1; off < 16; off <<= 1) rs += __shfl_xor(rs, off);
            lsum[r] = lsum[r] * al + rs;
            #pragma unroll
            for (int db = 0; db < 4; ++db) oa[db][r] *= al;
        }

        LGKM0();   // wave-local: P writes complete before P reads (wave-private rows)

        // ---- O += P V ----
        __builtin_amdgcn_s_setprio(1);
        #pragma unroll
        for (int ks = 0; ks < 2; ++ks) {
            int prow = w * 16 + l15, g2 = ks * 4 + g;
            int pidx = prow * 64 + ((g2 ^ (prow & 7)) << 3);
            bf16x8_t pah = __builtin_bit_cast(bf16x8_t, *(const ushort8_t*)&smem[KP_HI + pidx]);
            bf16x8_t pal = __builtin_bit_cast(bf16x8_t, *(const ushort8_t*)&smem[KP_LO + pidx]);
            #pragma unroll
            for (int db = 0; db < 4; ++db) {
                int vrow = db * 16 + l15;
                int vidx = vrow * 64 + ((g2 ^ (vrow & 7)) << 3);
                bf16x8_t vh = __builtin_bit_cast(bf16x8_t, *(const ushort8_t*)&smem[V_HI + vidx]);
                bf16x8_t vl = __builtin_bit_cast(bf16x8_t, *(const ushort8_t*)&smem[V_LO + vidx]);
                oa[db] = MFMA(pah, vh, oa[db]);
                oa[db] = MFMA(pah, vl, oa[db]);
                oa[db] = MFMA(pal, vh, oa[db]);
            }
        }
        __builtin_amdgcn_s_setprio(0);

        // ---- tail: all reads done, then land prefetched K/V(kt+1) ----
        if (kt + 1 < NT) {
            LGKM_BAR();
            *(ushort8_t*)&smem[KP_HI + dst0]        = skh0;
            *(ushort8_t*)&smem[KP_HI + dst0 + 2048] = skh1;
            *(ushort8_t*)&smem[KP_LO + dst0]        = skl0;
            *(ushort8_t*)&smem[KP_LO + dst0 + 2048] = skl1;
            *(ushort8_t*)&smem[V_HI + dst0]         = svh0;
            *(ushort8_t*)&smem[V_HI + dst0 + 2048]  = svh1;
            *(ushort8_t*)&smem[V_LO + dst0]         = svl0;
            *(ushort8_t*)&smem[V_LO + dst0 + 2048]  = svl1;
        }
    }

    // ---- epilogue: normalize, transpose to channel-major via LDS ----
    __syncthreads();
    float* Os = (float*)&smem[V_HI];   // 16 KiB scratch over V region
    #pragma unroll
    for (int db = 0; db < 4; ++db) {
        int d = db * 16 + l15;
        #pragma unroll
        for (int r = 0; r < 4; ++r) {
            int q = w * 16 + 4 * g + r;
            int oidx = d * 64 + (((q >> 2) ^ (d & 15)) << 2) + (q & 3);
            Os[oidx] = oa[db][r] / lsum[r];
        }
    }
    __syncthreads();
    {
        int d = tid >> 2, tg = tid & 3;
        float* og = out + ((size_t)n * CDIM + h * DHEAD + d) * TOK + t0;
        #pragma unroll
        for (int j = 0; j < 4; ++j) {
            int q4 = j * 4 + tg;
            float4 v = *(const float4*)&Os[d * 64 + ((q4 ^ (d & 15)) << 2)];
            *(float4*)&og[q4 * 4] = v;
        }
    }
}

// ---------------------------------------------------------------------------
extern "C" void kernel_launch(void* const* d_in, const int* in_sizes, int n_in,
                              void* d_out, int out_size, void* d_ws, size_t ws_size,
                              hipStream_t stream)
{
    const float* x    = (const float*)d_in[0];
    const float* mask = (const float*)d_in[1];
    const float* Wq   = (const float*)d_in[2];
    const float* bq   = (const float*)d_in[3];
    float* out = (float*)d_out;

    const size_t PL = (size_t)NB * NHEAD * TOK * DHEAD;
    unsigned short* qhi  = (unsigned short*)d_ws;
    unsigned short* qlo  = qhi  + PL;
    unsigned short* khi  = qlo  + PL;
    unsigned short* klo  = khi  + PL;
    unsigned short* vthi = klo  + PL;
    unsigned short* vtlo = vthi + PL;

    qkv_gemm<<<dim3(12, 64, 4), 256, 0, stream>>>(x, Wq, bq, mask,
                                                  qhi, qlo, khi, klo, vthi, vtlo);
    attn_mfma<<<dim3(1024), 256, 0, stream>>>(qhi, qlo, khi, klo, vthi, vtlo, out);
}

// Round 4
// 303.602 us; speedup vs baseline: 8.0044x; 1.5077x over previous
//
#include <hip/hip_runtime.h>
#include <math.h>

static constexpr int NB    = 4;
static constexpr int CDIM  = 256;
static constexpr int TOK   = 4096;
static constexpr int NHEAD = 4;
static constexpr int DHEAD = 64;
static constexpr int NT    = TOK / 64;   // 64 key-tiles of 64 keys

typedef short           bf16x8_t  __attribute__((ext_vector_type(8)));
typedef float           f32x4_t   __attribute__((ext_vector_type(4)));
typedef unsigned short  ushort8_t __attribute__((ext_vector_type(8)));
typedef unsigned int    uint4_t   __attribute__((ext_vector_type(4)));

__device__ __forceinline__ unsigned short f2bf_rne(float f) {
    unsigned x = __builtin_bit_cast(unsigned, f);
    x += 0x7fffu + ((x >> 16) & 1u);
    return (unsigned short)(x >> 16);
}
__device__ __forceinline__ float bf2f(unsigned short u) {
    return __builtin_bit_cast(float, (unsigned)u << 16);
}
__device__ __forceinline__ unsigned cvtpk(float lo, float hi) {
    unsigned r;
    asm("v_cvt_pk_bf16_f32 %0, %1, %2" : "=v"(r) : "v"(lo), "v"(hi));
    return r;
}

// ---------------------------------------------------------------------------
// Kernel 1: QKV projection (fp32 VALU GEMM). Epilogue emits bf16 hi/lo planes.
// mask * scale * log2(e) folded into q so attention softmax can use exp2.
// ---------------------------------------------------------------------------
__global__ __launch_bounds__(256)
void qkv_gemm(const float* __restrict__ x, const float* __restrict__ Wq,
              const float* __restrict__ bq, const float* __restrict__ mask,
              unsigned short* __restrict__ qhi, unsigned short* __restrict__ qlo,
              unsigned short* __restrict__ khi, unsigned short* __restrict__ klo,
              unsigned short* __restrict__ vthi, unsigned short* __restrict__ vtlo)
{
    const int col0 = blockIdx.x * 64;
    const int t0   = blockIdx.y * 64;
    const int n    = blockIdx.z;
    const int tid  = threadIdx.x;
    const int tx   = tid & 15, ty = tid >> 4;

    __shared__ float As[32][64];
    __shared__ float Bs[32][64];

    float acc[4][4] = {};
    const float* xn = x + (size_t)n * CDIM * TOK;

    for (int k0 = 0; k0 < CDIM; k0 += 32) {
        __syncthreads();
        #pragma unroll
        for (int i = 0; i < 2; ++i) {
            int idx = tid + i * 256;
            int cl = idx >> 4, q4 = idx & 15;
            *(float4*)&As[cl][q4 * 4] =
                *(const float4*)(xn + (size_t)(k0 + cl) * TOK + t0 + q4 * 4);
            *(float4*)&Bs[cl][q4 * 4] =
                *(const float4*)(Wq + (size_t)(k0 + cl) * 768 + col0 + q4 * 4);
        }
        __syncthreads();
        #pragma unroll
        for (int kk = 0; kk < 32; ++kk) {
            float4 a = *(const float4*)&As[kk][ty * 4];
            float4 b = *(const float4*)&Bs[kk][tx * 4];
            float ar[4] = {a.x, a.y, a.z, a.w};
            float br[4] = {b.x, b.y, b.z, b.w};
            #pragma unroll
            for (int r = 0; r < 4; ++r)
                #pragma unroll
                for (int c = 0; c < 4; ++c)
                    acc[r][c] += ar[r] * br[c];
        }
    }

    const int part = col0 >> 8;            // 0=q 1=k 2=v
    const int head = (col0 & 255) >> 6;
    const size_t hb = (size_t)(n * NHEAD + head) * TOK * DHEAD;
    float4 bias = *(const float4*)(bq + col0 + tx * 4);
    float bb[4] = {bias.x, bias.y, bias.z, bias.w};

    float vals[4][4];
    #pragma unroll
    for (int r = 0; r < 4; ++r)
        #pragma unroll
        for (int c = 0; c < 4; ++c)
            vals[r][c] = acc[r][c] + bb[c];

    if (part == 0) {
        #pragma unroll
        for (int r = 0; r < 4; ++r) {
            int t = t0 + ty * 4 + r;
            float mv = mask[(size_t)n * TOK + t] * 0.0625f * 1.4426950408889634f;
            #pragma unroll
            for (int c = 0; c < 4; ++c) vals[r][c] *= mv;
        }
    }

    if (part <= 1) {
        unsigned short* hp = (part == 0) ? qhi : khi;
        unsigned short* lp = (part == 0) ? qlo : klo;
        #pragma unroll
        for (int r = 0; r < 4; ++r) {
            int t = t0 + ty * 4 + r;
            ushort4 hh, ll;
            unsigned short* hc = (unsigned short*)&hh;
            unsigned short* lc = (unsigned short*)&ll;
            #pragma unroll
            for (int c = 0; c < 4; ++c) {
                hc[c] = f2bf_rne(vals[r][c]);
                lc[c] = f2bf_rne(vals[r][c] - bf2f(hc[c]));
            }
            *(ushort4*)&hp[hb + (size_t)t * DHEAD + tx * 4] = hh;
            *(ushort4*)&lp[hb + (size_t)t * DHEAD + tx * 4] = ll;
        }
    } else {
        #pragma unroll
        for (int c = 0; c < 4; ++c) {
            int d = tx * 4 + c;
            ushort4 hh, ll;
            unsigned short* hc = (unsigned short*)&hh;
            unsigned short* lc = (unsigned short*)&ll;
            #pragma unroll
            for (int r = 0; r < 4; ++r) {
                hc[r] = f2bf_rne(vals[r][c]);
                lc[r] = f2bf_rne(vals[r][c] - bf2f(hc[r]));
            }
            *(ushort4*)&vthi[hb + (size_t)d * TOK + t0 + ty * 4] = hh;
            *(ushort4*)&vtlo[hb + (size_t)d * TOK + t0 + ty * 4] = ll;
        }
    }
}

// ---------------------------------------------------------------------------
// Kernel 2: flash attention, swapped-QK MFMA, in-register P, QBLK=128.
//  - sa = mfma(K, Q): lane owns one q-row (q = w*16 + l15) -> lane-local softmax
//  - P redistributed to PV A-fragments with cvt_pk + 12 shfl_xor (no LDS P)
//  - PV = mfma(V, P): output col = q -> rescale/normalize stay lane-local
//  - 2 q-subtiles per wave (QBLK=128): K/V LDS reads amortized 2x
//  - 2 lgkm-only barriers per tile; register-staged K/V prefetch (T14)
// ---------------------------------------------------------------------------
#define MFMA(a, b, c) __builtin_amdgcn_mfma_f32_16x16x32_bf16((a), (b), (c), 0, 0, 0)
#define LGKM_BAR() asm volatile("s_waitcnt lgkmcnt(0)\n\ts_barrier" ::: "memory")

__global__ __launch_bounds__(256, 2)
void attn_mfma(const unsigned short* __restrict__ qhi, const unsigned short* __restrict__ qlo,
               const unsigned short* __restrict__ khi, const unsigned short* __restrict__ klo,
               const unsigned short* __restrict__ vthi, const unsigned short* __restrict__ vtlo,
               float* __restrict__ out)
{
    __shared__ __align__(16) unsigned char smem_raw[64 * 132 * 4];   // 33 KiB
    unsigned short* smem = (unsigned short*)smem_raw;
    constexpr int K_HI = 0, K_LO = 4096, V_HI = 8192, V_LO = 12288;  // ushort offs

    const int bid  = blockIdx.x;
    const int p    = (bid & 7) | (((bid >> 3) & 1) << 3);   // (n,head) 0..15
    const int tile = bid >> 4;                              // 0..31
    const int n = p >> 2, h = p & 3;
    const int t0 = tile * 128;

    const int tid  = threadIdx.x;
    const int lane = tid & 63, w = tid >> 6;
    const int l15  = lane & 15, g = lane >> 4;
    const int gr   = tid & 7, r2 = (tid >> 3) & 31;
    const int dst0 = r2 * 64 + ((gr ^ (r2 & 7)) << 3);

    const size_t base = (size_t)(n * NHEAD + h) * TOK * DHEAD;

    // ---- prologue: K/V(0) prefetch + Q fragments straight from global ----
    ushort8_t skh0, skh1, skl0, skl1, svh0, svh1, svl0, svl1;
    {
        size_t ks_ = base + (size_t)r2 * DHEAD + gr * 8;
        size_t vs_ = base + (size_t)r2 * TOK + gr * 8;
        skh0 = *(const ushort8_t*)&khi[ks_];
        skh1 = *(const ushort8_t*)&khi[ks_ + 32 * DHEAD];
        skl0 = *(const ushort8_t*)&klo[ks_];
        skl1 = *(const ushort8_t*)&klo[ks_ + 32 * DHEAD];
        svh0 = *(const ushort8_t*)&vthi[vs_];
        svh1 = *(const ushort8_t*)&vthi[vs_ + 32 * TOK];
        svl0 = *(const ushort8_t*)&vtlo[vs_];
        svl1 = *(const ushort8_t*)&vtlo[vs_ + 32 * TOK];
    }

    bf16x8_t qh[2][2], ql[2][2];
    #pragma unroll
    for (int u = 0; u < 2; ++u)
        #pragma unroll
        for (int ks = 0; ks < 2; ++ks) {
            size_t qa = base + (size_t)(t0 + u * 64 + w * 16 + l15) * DHEAD + ks * 32 + g * 8;
            qh[u][ks] = __builtin_bit_cast(bf16x8_t, *(const ushort8_t*)&qhi[qa]);
            ql[u][ks] = __builtin_bit_cast(bf16x8_t, *(const ushort8_t*)&qlo[qa]);
        }

    // stage K/V(0)
    *(ushort8_t*)&smem[K_HI + dst0]        = skh0;
    *(ushort8_t*)&smem[K_HI + dst0 + 2048] = skh1;
    *(ushort8_t*)&smem[K_LO + dst0]        = skl0;
    *(ushort8_t*)&smem[K_LO + dst0 + 2048] = skl1;
    *(ushort8_t*)&smem[V_HI + dst0]        = svh0;
    *(ushort8_t*)&smem[V_HI + dst0 + 2048] = svh1;
    *(ushort8_t*)&smem[V_LO + dst0]        = svl0;
    *(ushort8_t*)&smem[V_LO + dst0 + 2048] = svl1;

    float mreg[2] = {-1e30f, -1e30f}, lsum[2] = {0.f, 0.f};
    f32x4_t oa[2][4];
    #pragma unroll
    for (int u = 0; u < 2; ++u)
        #pragma unroll
        for (int db = 0; db < 4; ++db) oa[u][db] = (f32x4_t){0.f, 0.f, 0.f, 0.f};

    for (int kt = 0; kt < NT; ++kt) {
        LGKM_BAR();   // staged K/V(kt) visible (lgkm-only)

        // ---- prefetch K/V(kt+1) into regs (clamped on last iter) ----
        {
            int ktn = (kt + 1 < NT) ? kt + 1 : kt;
            size_t ks_ = base + (size_t)(ktn * 64 + r2) * DHEAD + gr * 8;
            size_t vs_ = base + (size_t)r2 * TOK + ktn * 64 + gr * 8;
            skh0 = *(const ushort8_t*)&khi[ks_];
            skh1 = *(const ushort8_t*)&khi[ks_ + 32 * DHEAD];
            skl0 = *(const ushort8_t*)&klo[ks_];
            skl1 = *(const ushort8_t*)&klo[ks_ + 32 * DHEAD];
            svh0 = *(const ushort8_t*)&vthi[vs_];
            svh1 = *(const ushort8_t*)&vthi[vs_ + 32 * TOK];
            svl0 = *(const ushort8_t*)&vtlo[vs_];
            svl1 = *(const ushort8_t*)&vtlo[vs_ + 32 * TOK];
        }

        // ---- S^T = K Q^T: sa[u][kb][r] = S[k = kb*16+g*4+r][q = u*64+w*16+l15]
        f32x4_t sa[2][4];
        #pragma unroll
        for (int u = 0; u < 2; ++u)
            #pragma unroll
            for (int kb = 0; kb < 4; ++kb) sa[u][kb] = (f32x4_t){0.f, 0.f, 0.f, 0.f};

        __builtin_amdgcn_s_setprio(1);
        #pragma unroll
        for (int ks = 0; ks < 2; ++ks) {
            #pragma unroll
            for (int kb = 0; kb < 4; ++kb) {
                int row = kb * 16 + l15;
                int idx = row * 64 + (((ks * 4 + g) ^ (row & 7)) << 3);
                bf16x8_t kh = __builtin_bit_cast(bf16x8_t, *(const ushort8_t*)&smem[K_HI + idx]);
                bf16x8_t kl = __builtin_bit_cast(bf16x8_t, *(const ushort8_t*)&smem[K_LO + idx]);
                sa[0][kb] = MFMA(kh, qh[0][ks], sa[0][kb]);
                sa[0][kb] = MFMA(kl, qh[0][ks], sa[0][kb]);
                sa[0][kb] = MFMA(kh, ql[0][ks], sa[0][kb]);
                sa[1][kb] = MFMA(kh, qh[1][ks], sa[1][kb]);
                sa[1][kb] = MFMA(kl, qh[1][ks], sa[1][kb]);
                sa[1][kb] = MFMA(kh, ql[1][ks], sa[1][kb]);
            }
        }
        __builtin_amdgcn_s_setprio(0);

        // ---- lane-local online softmax + in-register P redistribution ----
        bf16x8_t pa[2][2];
        #pragma unroll
        for (int u = 0; u < 2; ++u) {
            float mx = fmaxf(fmaxf(sa[u][0][0], sa[u][0][1]), fmaxf(sa[u][0][2], sa[u][0][3]));
            #pragma unroll
            for (int kb = 1; kb < 4; ++kb) {
                mx = fmaxf(mx, fmaxf(fmaxf(sa[u][kb][0], sa[u][kb][1]),
                                     fmaxf(sa[u][kb][2], sa[u][kb][3])));
            }
            mx = fmaxf(mx, __shfl_xor(mx, 16));
            mx = fmaxf(mx, __shfl_xor(mx, 32));
            if (!__all(mx <= mreg[u])) {          // exact deferred rescale
                float mn = fmaxf(mreg[u], mx);
                float al = __builtin_amdgcn_exp2f(mreg[u] - mn);
                mreg[u] = mn;
                lsum[u] *= al;
                #pragma unroll
                for (int db = 0; db < 4; ++db) {
                    oa[u][db][0] *= al; oa[u][db][1] *= al;
                    oa[u][db][2] *= al; oa[u][db][3] *= al;
                }
            }
            float pp[4][4];
            float rs = 0.f;
            #pragma unroll
            for (int kb = 0; kb < 4; ++kb)
                #pragma unroll
                for (int r = 0; r < 4; ++r) {
                    pp[kb][r] = __builtin_amdgcn_exp2f(sa[u][kb][r] - mreg[u]);
                    rs += pp[kb][r];
                }
            rs += __shfl_xor(rs, 16);
            rs += __shfl_xor(rs, 32);
            lsum[u] += rs;

            unsigned pk[4][2];
            #pragma unroll
            for (int kb = 0; kb < 4; ++kb) {
                pk[kb][0] = cvtpk(pp[kb][0], pp[kb][1]);
                pk[kb][1] = cvtpk(pp[kb][2], pp[kb][3]);
            }
            // redistribute: lane (q=l15, g') holds P[k=kb*16+g'*4+r][q];
            // PV A-frag needs lane (q=l15, g) octet: k = ks*32 + g*8 + j.
            #pragma unroll
            for (int ks = 0; ks < 2; ++ks) {
                unsigned a0, a1, a2, a3;
                #pragma unroll
                for (int hh = 0; hh < 2; ++hh) {
                    unsigned xa = (g & 1) ? pk[2 * ks][hh] : pk[2 * ks + 1][hh];
                    unsigned s16 = __shfl_xor((int)xa, 16);
                    unsigned s32 = __shfl_xor((int)xa, 32);
                    unsigned xb = (g & 1) ? pk[2 * ks + 1][hh] : pk[2 * ks][hh];
                    unsigned s48 = __shfl_xor((int)xb, 48);
                    unsigned alo = (g == 0) ? pk[2 * ks][hh]
                                 : (g == 1) ? s48
                                 : (g == 2) ? s32 : s16;
                    unsigned ahi = (g == 3) ? pk[2 * ks + 1][hh]
                                 : (g == 0) ? s16
                                 : (g == 1) ? s32 : s48;
                    if (hh == 0) { a0 = alo; a2 = ahi; }
                    else         { a1 = alo; a3 = ahi; }
                }
                uint4_t av = {a0, a1, a2, a3};
                pa[u][ks] = __builtin_bit_cast(bf16x8_t, av);
            }
        }

        // ---- O^acc += V^T P : oa[u][db] cols = q (lane-local) ----
        __builtin_amdgcn_s_setprio(1);
        #pragma unroll
        for (int ks = 0; ks < 2; ++ks) {
            #pragma unroll
            for (int db = 0; db < 4; ++db) {
                int vrow = db * 16 + l15;
                int vidx = vrow * 64 + (((ks * 4 + g) ^ (vrow & 7)) << 3);
                bf16x8_t vh = __builtin_bit_cast(bf16x8_t, *(const ushort8_t*)&smem[V_HI + vidx]);
                bf16x8_t vl = __builtin_bit_cast(bf16x8_t, *(const ushort8_t*)&smem[V_LO + vidx]);
                oa[0][db] = MFMA(vh, pa[0][ks], oa[0][db]);
                oa[0][db] = MFMA(vl, pa[0][ks], oa[0][db]);
                oa[1][db] = MFMA(vh, pa[1][ks], oa[1][db]);
                oa[1][db] = MFMA(vl, pa[1][ks], oa[1][db]);
            }
        }
        __builtin_amdgcn_s_setprio(0);

        LGKM_BAR();   // all reads of K/V(kt) complete

        if (kt + 1 < NT) {
            *(ushort8_t*)&smem[K_HI + dst0]        = skh0;
            *(ushort8_t*)&smem[K_HI + dst0 + 2048] = skh1;
            *(ushort8_t*)&smem[K_LO + dst0]        = skl0;
            *(ushort8_t*)&smem[K_LO + dst0 + 2048] = skl1;
            *(ushort8_t*)&smem[V_HI + dst0]        = svh0;
            *(ushort8_t*)&smem[V_HI + dst0 + 2048] = svh1;
            *(ushort8_t*)&smem[V_LO + dst0]        = svl0;
            *(ushort8_t*)&smem[V_LO + dst0 + 2048] = svl1;
        }
    }

    // ---- epilogue: normalize (lane-local), LDS transpose, coalesced store ----
    float* Os = (float*)smem_raw;   // [64 d][132 stride] floats
    #pragma unroll
    for (int u = 0; u < 2; ++u) {
        float rl = 1.0f / lsum[u];
        #pragma unroll
        for (int db = 0; db < 4; ++db)
            #pragma unroll
            for (int r = 0; r < 4; ++r)
                Os[(db * 16 + g * 4 + r) * 132 + u * 64 + w * 16 + l15] = oa[u][db][r] * rl;
    }
    LGKM_BAR();
    {
        int d = tid >> 2, qo = (tid & 3) * 32;
        float* og = out + ((size_t)n * CDIM + h * DHEAD + d) * TOK + t0 + qo;
        #pragma unroll
        for (int j = 0; j < 8; ++j)
            *(float4*)&og[j * 4] = *(const float4*)&Os[d * 132 + qo + j * 4];
    }
}

// ---------------------------------------------------------------------------
extern "C" void kernel_launch(void* const* d_in, const int* in_sizes, int n_in,
                              void* d_out, int out_size, void* d_ws, size_t ws_size,
                              hipStream_t stream)
{
    const float* x    = (const float*)d_in[0];
    const float* mask = (const float*)d_in[1];
    const float* Wq   = (const float*)d_in[2];
    const float* bq   = (const float*)d_in[3];
    float* out = (float*)d_out;

    const size_t PL = (size_t)NB * NHEAD * TOK * DHEAD;
    unsigned short* qhi  = (unsigned short*)d_ws;
    unsigned short* qlo  = qhi  + PL;
    unsigned short* khi  = qlo  + PL;
    unsigned short* klo  = khi  + PL;
    unsigned short* vthi = klo  + PL;
    unsigned short* vtlo = vthi + PL;

    qkv_gemm<<<dim3(12, 64, 4), 256, 0, stream>>>(x, Wq, bq, mask,
                                                  qhi, qlo, khi, klo, vthi, vtlo);
    attn_mfma<<<dim3(512), 256, 0, stream>>>(qhi, qlo, khi, klo, vthi, vtlo, out);
}

// Round 5
// 301.470 us; speedup vs baseline: 8.0610x; 1.0071x over previous
//
#include <hip/hip_runtime.h>
#include <math.h>

static constexpr int NB    = 4;
static constexpr int CDIM  = 256;
static constexpr int TOK   = 4096;
static constexpr int NHEAD = 4;
static constexpr int DHEAD = 64;
static constexpr int NT    = TOK / 64;   // 64 key-tiles of 64 keys

typedef short           bf16x8_t  __attribute__((ext_vector_type(8)));
typedef float           f32x4_t   __attribute__((ext_vector_type(4)));
typedef unsigned short  ushort8_t __attribute__((ext_vector_type(8)));
typedef unsigned int    uint4_t   __attribute__((ext_vector_type(4)));

__device__ __forceinline__ unsigned short f2bf_rne(float f) {
    unsigned x = __builtin_bit_cast(unsigned, f);
    x += 0x7fffu + ((x >> 16) & 1u);
    return (unsigned short)(x >> 16);
}
__device__ __forceinline__ float bf2f(unsigned short u) {
    return __builtin_bit_cast(float, (unsigned)u << 16);
}
__device__ __forceinline__ unsigned cvtpk(float lo, float hi) {
    unsigned r;
    asm("v_cvt_pk_bf16_f32 %0, %1, %2" : "=v"(r) : "v"(lo), "v"(hi));
    return r;
}

// ---------------------------------------------------------------------------
// Kernel 1: QKV projection (fp32 VALU GEMM). Epilogue emits bf16 hi/lo planes.
// mask * scale * log2(e) folded into q so attention softmax can use exp2.
// ---------------------------------------------------------------------------
__global__ __launch_bounds__(256)
void qkv_gemm(const float* __restrict__ x, const float* __restrict__ Wq,
              const float* __restrict__ bq, const float* __restrict__ mask,
              unsigned short* __restrict__ qhi, unsigned short* __restrict__ qlo,
              unsigned short* __restrict__ khi, unsigned short* __restrict__ klo,
              unsigned short* __restrict__ vthi, unsigned short* __restrict__ vtlo)
{
    const int col0 = blockIdx.x * 64;
    const int t0   = blockIdx.y * 64;
    const int n    = blockIdx.z;
    const int tid  = threadIdx.x;
    const int tx   = tid & 15, ty = tid >> 4;

    __shared__ float As[32][64];
    __shared__ float Bs[32][64];

    float acc[4][4] = {};
    const float* xn = x + (size_t)n * CDIM * TOK;

    for (int k0 = 0; k0 < CDIM; k0 += 32) {
        __syncthreads();
        #pragma unroll
        for (int i = 0; i < 2; ++i) {
            int idx = tid + i * 256;
            int cl = idx >> 4, q4 = idx & 15;
            *(float4*)&As[cl][q4 * 4] =
                *(const float4*)(xn + (size_t)(k0 + cl) * TOK + t0 + q4 * 4);
            *(float4*)&Bs[cl][q4 * 4] =
                *(const float4*)(Wq + (size_t)(k0 + cl) * 768 + col0 + q4 * 4);
        }
        __syncthreads();
        #pragma unroll
        for (int kk = 0; kk < 32; ++kk) {
            float4 a = *(const float4*)&As[kk][ty * 4];
            float4 b = *(const float4*)&Bs[kk][tx * 4];
            float ar[4] = {a.x, a.y, a.z, a.w};
            float br[4] = {b.x, b.y, b.z, b.w};
            #pragma unroll
            for (int r = 0; r < 4; ++r)
                #pragma unroll
                for (int c = 0; c < 4; ++c)
                    acc[r][c] += ar[r] * br[c];
        }
    }

    const int part = col0 >> 8;            // 0=q 1=k 2=v
    const int head = (col0 & 255) >> 6;
    const size_t hb = (size_t)(n * NHEAD + head) * TOK * DHEAD;
    float4 bias = *(const float4*)(bq + col0 + tx * 4);
    float bb[4] = {bias.x, bias.y, bias.z, bias.w};

    float vals[4][4];
    #pragma unroll
    for (int r = 0; r < 4; ++r)
        #pragma unroll
        for (int c = 0; c < 4; ++c)
            vals[r][c] = acc[r][c] + bb[c];

    if (part == 0) {
        #pragma unroll
        for (int r = 0; r < 4; ++r) {
            int t = t0 + ty * 4 + r;
            float mv = mask[(size_t)n * TOK + t] * 0.0625f * 1.4426950408889634f;
            #pragma unroll
            for (int c = 0; c < 4; ++c) vals[r][c] *= mv;
        }
    }

    if (part <= 1) {
        unsigned short* hp = (part == 0) ? qhi : khi;
        unsigned short* lp = (part == 0) ? qlo : klo;
        #pragma unroll
        for (int r = 0; r < 4; ++r) {
            int t = t0 + ty * 4 + r;
            ushort4 hh, ll;
            unsigned short* hc = (unsigned short*)&hh;
            unsigned short* lc = (unsigned short*)&ll;
            #pragma unroll
            for (int c = 0; c < 4; ++c) {
                hc[c] = f2bf_rne(vals[r][c]);
                lc[c] = f2bf_rne(vals[r][c] - bf2f(hc[c]));
            }
            *(ushort4*)&hp[hb + (size_t)t * DHEAD + tx * 4] = hh;
            *(ushort4*)&lp[hb + (size_t)t * DHEAD + tx * 4] = ll;
        }
    } else {
        #pragma unroll
        for (int c = 0; c < 4; ++c) {
            int d = tx * 4 + c;
            ushort4 hh, ll;
            unsigned short* hc = (unsigned short*)&hh;
            unsigned short* lc = (unsigned short*)&ll;
            #pragma unroll
            for (int r = 0; r < 4; ++r) {
                hc[r] = f2bf_rne(vals[r][c]);
                lc[r] = f2bf_rne(vals[r][c] - bf2f(hc[r]));
            }
            *(ushort4*)&vthi[hb + (size_t)d * TOK + t0 + ty * 4] = hh;
            *(ushort4*)&vtlo[hb + (size_t)d * TOK + t0 + ty * 4] = ll;
        }
    }
}

// ---------------------------------------------------------------------------
// Kernel 2: flash attention, swapped-QK MFMA, in-register P, QBLK=128.
//  - sa = mfma(K, Q): lane owns one q-row (q = w*16 + l15) -> lane-local softmax
//  - P redistributed to PV A-fragments with cvt_pk + 12 shfl_xor (no LDS P)
//  - PV = mfma(V, P): output col = q -> rescale/normalize stay lane-local
//  - 2 q-subtiles per wave (QBLK=128): K/V LDS reads amortized 2x
//  - 2 lgkm-only barriers per tile; register-staged K/V prefetch (T14)
// ---------------------------------------------------------------------------
#define MFMA(a, b, c) __builtin_amdgcn_mfma_f32_16x16x32_bf16((a), (b), (c), 0, 0, 0)
#define LGKM_BAR() asm volatile("s_waitcnt lgkmcnt(0)\n\ts_barrier" ::: "memory")

__global__ __launch_bounds__(256, 2)
void attn_mfma(const unsigned short* __restrict__ qhi, const unsigned short* __restrict__ qlo,
               const unsigned short* __restrict__ khi, const unsigned short* __restrict__ klo,
               const unsigned short* __restrict__ vthi, const unsigned short* __restrict__ vtlo,
               float* __restrict__ out)
{
    __shared__ __align__(16) unsigned char smem_raw[64 * 132 * 4];   // 33 KiB
    unsigned short* smem = (unsigned short*)smem_raw;
    constexpr int K_HI = 0, K_LO = 4096, V_HI = 8192, V_LO = 12288;  // ushort offs

    const int bid  = blockIdx.x;
    const int p    = (bid & 7) | (((bid >> 3) & 1) << 3);   // (n,head) 0..15
    const int tile = bid >> 4;                              // 0..31
    const int n = p >> 2, h = p & 3;
    const int t0 = tile * 128;

    const int tid  = threadIdx.x;
    const int lane = tid & 63, w = tid >> 6;
    const int l15  = lane & 15, g = lane >> 4;
    const int gr   = tid & 7, r2 = (tid >> 3) & 31;
    const int dst0 = r2 * 64 + ((gr ^ (r2 & 7)) << 3);

    const size_t base = (size_t)(n * NHEAD + h) * TOK * DHEAD;

    // ---- prologue: K/V(0) prefetch + Q fragments straight from global ----
    ushort8_t skh0, skh1, skl0, skl1, svh0, svh1, svl0, svl1;
    {
        size_t ks_ = base + (size_t)r2 * DHEAD + gr * 8;
        size_t vs_ = base + (size_t)r2 * TOK + gr * 8;
        skh0 = *(const ushort8_t*)&khi[ks_];
        skh1 = *(const ushort8_t*)&khi[ks_ + 32 * DHEAD];
        skl0 = *(const ushort8_t*)&klo[ks_];
        skl1 = *(const ushort8_t*)&klo[ks_ + 32 * DHEAD];
        svh0 = *(const ushort8_t*)&vthi[vs_];
        svh1 = *(const ushort8_t*)&vthi[vs_ + 32 * TOK];
        svl0 = *(const ushort8_t*)&vtlo[vs_];
        svl1 = *(const ushort8_t*)&vtlo[vs_ + 32 * TOK];
    }

    bf16x8_t qh[2][2], ql[2][2];
    #pragma unroll
    for (int u = 0; u < 2; ++u)
        #pragma unroll
        for (int ks = 0; ks < 2; ++ks) {
            size_t qa = base + (size_t)(t0 + u * 64 + w * 16 + l15) * DHEAD + ks * 32 + g * 8;
            qh[u][ks] = __builtin_bit_cast(bf16x8_t, *(const ushort8_t*)&qhi[qa]);
            ql[u][ks] = __builtin_bit_cast(bf16x8_t, *(const ushort8_t*)&qlo[qa]);
        }

    // stage K/V(0)
    *(ushort8_t*)&smem[K_HI + dst0]        = skh0;
    *(ushort8_t*)&smem[K_HI + dst0 + 2048] = skh1;
    *(ushort8_t*)&smem[K_LO + dst0]        = skl0;
    *(ushort8_t*)&smem[K_LO + dst0 + 2048] = skl1;
    *(ushort8_t*)&smem[V_HI + dst0]        = svh0;
    *(ushort8_t*)&smem[V_HI + dst0 + 2048] = svh1;
    *(ushort8_t*)&smem[V_LO + dst0]        = svl0;
    *(ushort8_t*)&smem[V_LO + dst0 + 2048] = svl1;

    float mreg[2] = {-1e30f, -1e30f}, lsum[2] = {0.f, 0.f};
    f32x4_t oa[2][4];
    #pragma unroll
    for (int u = 0; u < 2; ++u)
        #pragma unroll
        for (int db = 0; db < 4; ++db) oa[u][db] = (f32x4_t){0.f, 0.f, 0.f, 0.f};

    for (int kt = 0; kt < NT; ++kt) {
        LGKM_BAR();   // staged K/V(kt) visible (lgkm-only)

        // ---- prefetch K/V(kt+1) into regs (clamped on last iter) ----
        {
            int ktn = (kt + 1 < NT) ? kt + 1 : kt;
            size_t ks_ = base + (size_t)(ktn * 64 + r2) * DHEAD + gr * 8;
            size_t vs_ = base + (size_t)r2 * TOK + ktn * 64 + gr * 8;
            skh0 = *(const ushort8_t*)&khi[ks_];
            skh1 = *(const ushort8_t*)&khi[ks_ + 32 * DHEAD];
            skl0 = *(const ushort8_t*)&klo[ks_];
            skl1 = *(const ushort8_t*)&klo[ks_ + 32 * DHEAD];
            svh0 = *(const ushort8_t*)&vthi[vs_];
            svh1 = *(const ushort8_t*)&vthi[vs_ + 32 * TOK];
            svl0 = *(const ushort8_t*)&vtlo[vs_];
            svl1 = *(const ushort8_t*)&vtlo[vs_ + 32 * TOK];
        }

        // ---- S^T = K Q^T: sa[u][kb][r] = S[k = kb*16+g*4+r][q = u*64+w*16+l15]
        f32x4_t sa[2][4];
        #pragma unroll
        for (int u = 0; u < 2; ++u)
            #pragma unroll
            for (int kb = 0; kb < 4; ++kb) sa[u][kb] = (f32x4_t){0.f, 0.f, 0.f, 0.f};

        __builtin_amdgcn_s_setprio(1);
        #pragma unroll
        for (int ks = 0; ks < 2; ++ks) {
            #pragma unroll
            for (int kb = 0; kb < 4; ++kb) {
                int row = kb * 16 + l15;
                int idx = row * 64 + (((ks * 4 + g) ^ (row & 7)) << 3);
                bf16x8_t kh = __builtin_bit_cast(bf16x8_t, *(const ushort8_t*)&smem[K_HI + idx]);
                bf16x8_t kl = __builtin_bit_cast(bf16x8_t, *(const ushort8_t*)&smem[K_LO + idx]);
                sa[0][kb] = MFMA(kh, qh[0][ks], sa[0][kb]);
                sa[0][kb] = MFMA(kl, qh[0][ks], sa[0][kb]);
                sa[0][kb] = MFMA(kh, ql[0][ks], sa[0][kb]);
                sa[1][kb] = MFMA(kh, qh[1][ks], sa[1][kb]);
                sa[1][kb] = MFMA(kl, qh[1][ks], sa[1][kb]);
                sa[1][kb] = MFMA(kh, ql[1][ks], sa[1][kb]);
            }
        }
        __builtin_amdgcn_s_setprio(0);

        // ---- lane-local online softmax + in-register P redistribution ----
        bf16x8_t pa[2][2];
        #pragma unroll
        for (int u = 0; u < 2; ++u) {
            float mx = fmaxf(fmaxf(sa[u][0][0], sa[u][0][1]), fmaxf(sa[u][0][2], sa[u][0][3]));
            #pragma unroll
            for (int kb = 1; kb < 4; ++kb) {
                mx = fmaxf(mx, fmaxf(fmaxf(sa[u][kb][0], sa[u][kb][1]),
                                     fmaxf(sa[u][kb][2], sa[u][kb][3])));
            }
            mx = fmaxf(mx, __shfl_xor(mx, 16));
            mx = fmaxf(mx, __shfl_xor(mx, 32));
            if (!__all(mx <= mreg[u])) {          // exact deferred rescale
                float mn = fmaxf(mreg[u], mx);
                float al = __builtin_amdgcn_exp2f(mreg[u] - mn);
                mreg[u] = mn;
                lsum[u] *= al;
                #pragma unroll
                for (int db = 0; db < 4; ++db) {
                    oa[u][db][0] *= al; oa[u][db][1] *= al;
                    oa[u][db][2] *= al; oa[u][db][3] *= al;
                }
            }
            float pp[4][4];
            float rs = 0.f;
            #pragma unroll
            for (int kb = 0; kb < 4; ++kb)
                #pragma unroll
                for (int r = 0; r < 4; ++r) {
                    pp[kb][r] = __builtin_amdgcn_exp2f(sa[u][kb][r] - mreg[u]);
                    rs += pp[kb][r];
                }
            rs += __shfl_xor(rs, 16);
            rs += __shfl_xor(rs, 32);
            lsum[u] += rs;

            unsigned pk[4][2];
            #pragma unroll
            for (int kb = 0; kb < 4; ++kb) {
                pk[kb][0] = cvtpk(pp[kb][0], pp[kb][1]);
                pk[kb][1] = cvtpk(pp[kb][2], pp[kb][3]);
            }
            // redistribute: lane (q=l15, g') holds P[k=kb*16+g'*4+r][q];
            // PV A-frag needs lane (q=l15, g) octet: k = ks*32 + g*8 + j.
            #pragma unroll
            for (int ks = 0; ks < 2; ++ks) {
                unsigned a0, a1, a2, a3;
                #pragma unroll
                for (int hh = 0; hh < 2; ++hh) {
                    unsigned xa = (g & 1) ? pk[2 * ks][hh] : pk[2 * ks + 1][hh];
                    unsigned s16 = __shfl_xor((int)xa, 16);
                    unsigned s32 = __shfl_xor((int)xa, 32);
                    unsigned xb = (g & 1) ? pk[2 * ks + 1][hh] : pk[2 * ks][hh];
                    unsigned s48 = __shfl_xor((int)xb, 48);
                    unsigned alo = (g == 0) ? pk[2 * ks][hh]
                                 : (g == 1) ? s48
                                 : (g == 2) ? s32 : s16;
                    unsigned ahi = (g == 3) ? pk[2 * ks + 1][hh]
                                 : (g == 0) ? s16
                                 : (g == 1) ? s32 : s48;
                    if (hh == 0) { a0 = alo; a2 = ahi; }
                    else         { a1 = alo; a3 = ahi; }
                }
                uint4_t av = {a0, a1, a2, a3};
                pa[u][ks] = __builtin_bit_cast(bf16x8_t, av);
            }
        }

        // ---- O^acc += V^T P : oa[u][db] cols = q (lane-local) ----
        __builtin_amdgcn_s_setprio(1);
        #pragma unroll
        for (int ks = 0; ks < 2; ++ks) {
            #pragma unroll
            for (int db = 0; db < 4; ++db) {
                int vrow = db * 16 + l15;
                int vidx = vrow * 64 + (((ks * 4 + g) ^ (vrow & 7)) << 3);
                bf16x8_t vh = __builtin_bit_cast(bf16x8_t, *(const ushort8_t*)&smem[V_HI + vidx]);
                bf16x8_t vl = __builtin_bit_cast(bf16x8_t, *(const ushort8_t*)&smem[V_LO + vidx]);
                oa[0][db] = MFMA(vh, pa[0][ks], oa[0][db]);
                oa[0][db] = MFMA(vl, pa[0][ks], oa[0][db]);
                oa[1][db] = MFMA(vh, pa[1][ks], oa[1][db]);
                oa[1][db] = MFMA(vl, pa[1][ks], oa[1][db]);
            }
        }
        __builtin_amdgcn_s_setprio(0);

        LGKM_BAR();   // all reads of K/V(kt) complete

        if (kt + 1 < NT) {
            *(ushort8_t*)&smem[K_HI + dst0]        = skh0;
            *(ushort8_t*)&smem[K_HI + dst0 + 2048] = skh1;
            *(ushort8_t*)&smem[K_LO + dst0]        = skl0;
            *(ushort8_t*)&smem[K_LO + dst0 + 2048] = skl1;
            *(ushort8_t*)&smem[V_HI + dst0]        = svh0;
            *(ushort8_t*)&smem[V_HI + dst0 + 2048] = svh1;
            *(ushort8_t*)&smem[V_LO + dst0]        = svl0;
            *(ushort8_t*)&smem[V_LO + dst0 + 2048] = svl1;
        }
    }

    // ---- epilogue: normalize (lane-local), LDS transpose, coalesced store ----
    float* Os = (float*)smem_raw;   // [64 d][132 stride] floats
    #pragma unroll
    for (int u = 0; u < 2; ++u) {
        float rl = 1.0f / lsum[u];
        #pragma unroll
        for (int db = 0; db < 4; ++db)
            #pragma unroll
            for (int r = 0; r < 4; ++r)
                Os[(db * 16 + g * 4 + r) * 132 + u * 64 + w * 16 + l15] = oa[u][db][r] * rl;
    }
    LGKM_BAR();
    {
        int d = tid >> 2, qo = (tid & 3) * 32;
        float* og = out + ((size_t)n * CDIM + h * DHEAD + d) * TOK + t0 + qo;
        #pragma unroll
        for (int j = 0; j < 8; ++j)
            *(float4*)&og[j * 4] = *(const float4*)&Os[d * 132 + qo + j * 4];
    }
}

// ---------------------------------------------------------------------------
extern "C" void kernel_launch(void* const* d_in, const int* in_sizes, int n_in,
                              void* d_out, int out_size, void* d_ws, size_t ws_size,
                              hipStream_t stream)
{
    const float* x    = (const float*)d_in[0];
    const float* mask = (const float*)d_in[1];
    const float* Wq   = (const float*)d_in[2];
    const float* bq   = (const float*)d_in[3];
    float* out = (float*)d_out;

    const size_t PL = (size_t)NB * NHEAD * TOK * DHEAD;
    unsigned short* qhi  = (unsigned short*)d_ws;
    unsigned short* qlo  = qhi  + PL;
    unsigned short* khi  = qlo  + PL;
    unsigned short* klo  = khi  + PL;
    unsigned short* vthi = klo  + PL;
    unsigned short* vtlo = vthi + PL;

    qkv_gemm<<<dim3(12, 64, 4), 256, 0, stream>>>(x, Wq, bq, mask,
                                                  qhi, qlo, khi, klo, vthi, vtlo);
    attn_mfma<<<dim3(512), 256, 0, stream>>>(qhi, qlo, khi, klo, vthi, vtlo, out);
}